// Round 1
// baseline (262.841 us; speedup 1.0000x reference)
//
#include <hip/hip_runtime.h>
#include <hip/hip_bf16.h>
#include <math.h>

// Problem constants (B,S,D,H fixed by the reference)
constexpr int Bb  = 2;
constexpr int Ss  = 2048;
constexpr int Dd  = 1024;
constexpr int Hh  = 16;
constexpr int DKk = 64;
constexpr int Mm  = Bb * Ss;   // 4096 rows

typedef unsigned short u16;
typedef __attribute__((ext_vector_type(8))) short short8;   // 8 bf16 = 16B (MFMA frag)
typedef __attribute__((ext_vector_type(4))) short short4v;  // 8B
typedef __attribute__((ext_vector_type(4))) float f32x4;
typedef __attribute__((ext_vector_type(4))) int   int4v;

static __device__ __forceinline__ u16 f2bf(float f) {
  union { float f; unsigned u; } c; c.f = f;
  unsigned u = c.u;
  unsigned r = u + 0x7FFFu + ((u >> 16) & 1u);  // RNE
  return (u16)(r >> 16);
}

// ---------------------------------------------------------------------------
// 1) fp32 -> bf16 convert of query/key/value into ws (3 contiguous arrays)
// ---------------------------------------------------------------------------
__global__ __launch_bounds__(256) void cvt_inputs(
    const float* __restrict__ q, const float* __restrict__ k,
    const float* __restrict__ v, u16* __restrict__ outA)
{
  const size_t per = (size_t)Mm * Dd / 4;  // float4 groups per array (2^20)
  const size_t tot = 3 * per;
  for (size_t i = (size_t)blockIdx.x * blockDim.x + threadIdx.x; i < tot;
       i += (size_t)gridDim.x * blockDim.x) {
    const float* src; size_t idx;
    if (i < per)            { src = q; idx = i; }
    else if (i < 2 * per)   { src = k; idx = i - per; }
    else                    { src = v; idx = i - 2 * per; }
    f32x4 f = ((const f32x4*)src)[idx];
    short4v o;
    o[0] = (short)f2bf(f[0]); o[1] = (short)f2bf(f[1]);
    o[2] = (short)f2bf(f[2]); o[3] = (short)f2bf(f[3]);
    ((short4v*)outA)[i] = o;
  }
}

// ---------------------------------------------------------------------------
// 2) Weight transpose + convert: WT[z][n][k] = W_z[k][n] as bf16
// grid (16,16,4), 256 threads, 64x64 tiles
// ---------------------------------------------------------------------------
__global__ __launch_bounds__(256) void wt_transpose(
    const float* __restrict__ wq, const float* __restrict__ wk,
    const float* __restrict__ wv, const float* __restrict__ wo,
    u16* __restrict__ outWT)
{
  __shared__ float tile[64][65];
  const int z = blockIdx.z;
  const float* w = (z == 0) ? wq : (z == 1) ? wk : (z == 2) ? wv : wo;
  const int n0 = blockIdx.x * 64, k0 = blockIdx.y * 64;
  const int t = threadIdx.x;
  {
    const int r = t >> 2, u = t & 3;
    #pragma unroll
    for (int e = 0; e < 4; e++) {
      f32x4 f = *(const f32x4*)(w + (size_t)(k0 + r) * Dd + n0 + u * 16 + e * 4);
      tile[r][u * 16 + e * 4 + 0] = f[0];
      tile[r][u * 16 + e * 4 + 1] = f[1];
      tile[r][u * 16 + e * 4 + 2] = f[2];
      tile[r][u * 16 + e * 4 + 3] = f[3];
    }
  }
  __syncthreads();
  {
    const int n = t >> 2, u = t & 3;
    u16 tmp[16];
    #pragma unroll
    for (int e = 0; e < 16; e++) tmp[e] = f2bf(tile[u * 16 + e][n]);
    short8 o0, o1;
    #pragma unroll
    for (int j = 0; j < 8; j++) { o0[j] = (short)tmp[j]; o1[j] = (short)tmp[8 + j]; }
    u16* dst = outWT + (size_t)z * Dd * Dd + (size_t)(n0 + n) * Dd + k0 + u * 16;
    *(short8*)dst       = o0;
    *(short8*)(dst + 8) = o1;
  }
}

// ---------------------------------------------------------------------------
// 3) Mask summary: flag[b][qt][kt] = any zero in 64x64 tile. grid 2048.
// ---------------------------------------------------------------------------
__global__ __launch_bounds__(256) void mask_flags(
    const int* __restrict__ mask, int* __restrict__ flags)
{
  const int fid = blockIdx.x;
  const int b = fid >> 10, qt = (fid >> 5) & 31, kt = fid & 31;
  const int t = threadIdx.x;
  int hasz = 0;
  #pragma unroll
  for (int e = 0; e < 4; e++) {
    int c = t + 256 * e;               // 0..1023 int4 chunks
    int row = c >> 4, c4 = c & 15;
    int4v mv = *(const int4v*)(mask + ((size_t)b * Ss + qt * 64 + row) * Ss + kt * 64 + c4 * 4);
    hasz |= (mv[0] == 0) | (mv[1] == 0) | (mv[2] == 0) | (mv[3] == 0);
  }
  __shared__ int red;
  if (t == 0) red = 0;
  __syncthreads();
  if (hasz) atomicOr(&red, 1);
  __syncthreads();
  if (t == 0) flags[fid] = red;
}

// ---------------------------------------------------------------------------
// 4) Fused QKV projection GEMM. 128x128 tile, BK=32, 4 waves (2x2), bf16 MFMA.
// z=0 -> Qh[b][h][s][dk], z=1 -> Kh (same), z=2 -> Vt[b][h][dk][s] (transposed)
// LDS rows padded to 40 u16 (80B) -> frag reads are 2-way conflicts (free).
// ---------------------------------------------------------------------------
__global__ __launch_bounds__(256) void gemm_qkv(
    const u16* __restrict__ Aall, const u16* __restrict__ WT,
    const float* __restrict__ bq, const float* __restrict__ bk,
    const float* __restrict__ bv,
    u16* __restrict__ Qh, u16* __restrict__ Kh, u16* __restrict__ Vt)
{
  const int z = blockIdx.z;
  const u16* A  = Aall + (size_t)z * Mm * Dd;
  const u16* Bw = WT   + (size_t)z * Dd * Dd;
  const float* bias = (z == 0) ? bq : (z == 1) ? bk : bv;
  const int mbase = blockIdx.y * 128, nbase = blockIdx.x * 128;

  __shared__ u16 lA[128][40];
  __shared__ u16 lB[128][40];

  const int t = threadIdx.x, lane = t & 63, w = t >> 6;
  const int wr = w >> 1, wc = w & 1, lg = lane >> 4, lr = lane & 15;

  f32x4 acc[4][4];
  #pragma unroll
  for (int mf = 0; mf < 4; mf++)
    #pragma unroll
    for (int nf = 0; nf < 4; nf++) acc[mf][nf] = (f32x4){0.f, 0.f, 0.f, 0.f};

  for (int kk = 0; kk < Dd; kk += 32) {
    #pragma unroll
    for (int i = 0; i < 2; i++) {
      int c = t + 256 * i, row = c >> 2, u = c & 3;
      *(short8*)&lA[row][u * 8] = *(const short8*)(A  + (size_t)(mbase + row) * Dd + kk + u * 8);
      *(short8*)&lB[row][u * 8] = *(const short8*)(Bw + (size_t)(nbase + row) * Dd + kk + u * 8);
    }
    __syncthreads();
    short8 af[4], bfr[4];
    #pragma unroll
    for (int mf = 0; mf < 4; mf++) af[mf]  = *(const short8*)&lA[wr * 64 + mf * 16 + lr][lg * 8];
    #pragma unroll
    for (int nf = 0; nf < 4; nf++) bfr[nf] = *(const short8*)&lB[wc * 64 + nf * 16 + lr][lg * 8];
    #pragma unroll
    for (int mf = 0; mf < 4; mf++)
      #pragma unroll
      for (int nf = 0; nf < 4; nf++)
        acc[mf][nf] = __builtin_amdgcn_mfma_f32_16x16x32_bf16(af[mf], bfr[nf], acc[mf][nf], 0, 0, 0);
    __syncthreads();
  }

  #pragma unroll
  for (int nf = 0; nf < 4; nf++) {
    const int n = nbase + wc * 64 + nf * 16 + lr;
    const float bb = bias[n];
    const int h = n >> 6, dk = n & 63;
    #pragma unroll
    for (int mf = 0; mf < 4; mf++) {
      const int m0 = mbase + wr * 64 + mf * 16 + lg * 4;
      const int b = m0 >> 11, s0 = m0 & 2047;
      if (z == 2) {
        short4v o;
        #pragma unroll
        for (int r = 0; r < 4; r++) o[r] = (short)f2bf(acc[mf][nf][r] + bb);
        *(short4v*)(Vt + ((size_t)(b * Hh + h) * DKk + dk) * Ss + s0) = o;
      } else {
        u16* out = (z == 0) ? Qh : Kh;
        #pragma unroll
        for (int r = 0; r < 4; r++)
          out[((size_t)(b * Hh + h) * Ss + s0 + r) * DKk + dk] = f2bf(acc[mf][nf][r] + bb);
      }
    }
  }
}

// ---------------------------------------------------------------------------
// 5) Flash attention with ALiBi. Block = 256 thr (4 waves), per (b,h,64 q-rows).
// Each wave owns 16 q-rows; KV tiles of 64; online softmax; P via per-wave LDS.
// ---------------------------------------------------------------------------
__global__ __launch_bounds__(256) void attn_kernel(
    const u16* __restrict__ Qh, const u16* __restrict__ Kh, const u16* __restrict__ Vt,
    const int* __restrict__ mask, const int* __restrict__ flags, u16* __restrict__ AO)
{
  const int qt = blockIdx.x, h = blockIdx.y, b = blockIdx.z;
  const int t = threadIdx.x, lane = t & 63, w = t >> 6;
  const int lg = lane >> 4, lr = lane & 15;

  __shared__ u16 lK[64][72];        // [key][dk], 144B rows
  __shared__ u16 lV[64][72];        // [dk][key] (Vt layout), 144B rows
  __shared__ u16 lP[4][16][72];     // per-wave P, [q][key]

  const u16* Qp = Qh + ((size_t)(b * Hh + h) * Ss + qt * 64) * DKk;
  const u16* Kp = Kh + ((size_t)(b * Hh + h) * Ss) * DKk;
  const u16* Vp = Vt + ((size_t)(b * Hh + h) * DKk) * Ss;

  // Q fragments for this wave's 16 rows (kept in registers, unscaled)
  const short8 qf0 = *(const short8*)(Qp + (w * 16 + lr) * DKk + lg * 8);
  const short8 qf1 = *(const short8*)(Qp + (w * 16 + lr) * DKk + 32 + lg * 8);

  const float slope = exp2f(-0.5f * (float)(h + 1));  // 2^(-8(h+1)/H), H=16

  f32x4 accO[4];
  #pragma unroll
  for (int nf = 0; nf < 4; nf++) accO[nf] = (f32x4){0.f, 0.f, 0.f, 0.f};
  float mrun[4], lrun[4];
  #pragma unroll
  for (int r = 0; r < 4; r++) { mrun[r] = -__builtin_inff(); lrun[r] = 0.f; }

  const int qg0 = qt * 64 + w * 16 + lg * 4;  // this lane's first q row (D-frag rows)

  for (int kt = 0; kt < Ss / 64; kt++) {
    if (kt) __syncthreads();
    #pragma unroll
    for (int i = 0; i < 2; i++) {
      int c = t + 256 * i;
      int row = c >> 3, u = c & 7;
      *(short8*)&lK[row][u * 8] = *(const short8*)(Kp + (size_t)(kt * 64 + row) * DKk + u * 8);
      *(short8*)&lV[row][u * 8] = *(const short8*)(Vp + (size_t)row * Ss + kt * 64 + u * 8);
    }
    __syncthreads();

    // S = Q K^T : D-frag col = key (lr + 16*kf), row = q (lg*4 + r)
    f32x4 sf[4];
    #pragma unroll
    for (int kf = 0; kf < 4; kf++) {
      short8 kb0 = *(const short8*)&lK[kf * 16 + lr][lg * 8];
      short8 kb1 = *(const short8*)&lK[kf * 16 + lr][32 + lg * 8];
      f32x4 zacc = (f32x4){0.f, 0.f, 0.f, 0.f};
      zacc = __builtin_amdgcn_mfma_f32_16x16x32_bf16(qf0, kb0, zacc, 0, 0, 0);
      zacc = __builtin_amdgcn_mfma_f32_16x16x32_bf16(qf1, kb1, zacc, 0, 0, 0);
      sf[kf] = zacc;
    }

    const int flagv = flags[(b * 32 + qt) * 32 + kt];
    float bs[4][4];
    #pragma unroll
    for (int kf = 0; kf < 4; kf++) {
      const int kg = kt * 64 + kf * 16 + lr;
      #pragma unroll
      for (int r = 0; r < 4; r++) {
        int di = (qg0 + r) - kg; di = di < 0 ? -di : di;
        float vsc = sf[kf][r] * 0.125f - slope * (float)di;  // 1/sqrt(64) fold
        if (flagv) {
          if (mask[((size_t)b * Ss + (qg0 + r)) * Ss + kg] == 0) vsc = -__builtin_inff();
        }
        bs[kf][r] = vsc;
      }
    }

    // row max over 64 keys: 4 local + butterfly over the 16 key-lanes
    float mx[4];
    #pragma unroll
    for (int r = 0; r < 4; r++)
      mx[r] = fmaxf(fmaxf(bs[0][r], bs[1][r]), fmaxf(bs[2][r], bs[3][r]));
    #pragma unroll
    for (int d = 1; d < 16; d <<= 1)
      #pragma unroll
      for (int r = 0; r < 4; r++) mx[r] = fmaxf(mx[r], __shfl_xor(mx[r], d));

    float mneff[4], scalef[4];
    #pragma unroll
    for (int r = 0; r < 4; r++) {
      float mn = fmaxf(mrun[r], mx[r]);
      float me = (mn == -__builtin_inff()) ? 0.f : mn;  // fully-masked guard
      scalef[r] = __expf(mrun[r] - me);
      mrun[r] = mn; mneff[r] = me;
    }

    float ps[4] = {0.f, 0.f, 0.f, 0.f};
    #pragma unroll
    for (int kf = 0; kf < 4; kf++)
      #pragma unroll
      for (int r = 0; r < 4; r++) {
        float p = __expf(bs[kf][r] - mneff[r]);
        ps[r] += p;
        lP[w][lg * 4 + r][kf * 16 + lr] = f2bf(p);
      }
    #pragma unroll
    for (int d = 1; d < 16; d <<= 1)
      #pragma unroll
      for (int r = 0; r < 4; r++) ps[r] += __shfl_xor(ps[r], d);
    #pragma unroll
    for (int r = 0; r < 4; r++) lrun[r] = lrun[r] * scalef[r] + ps[r];
    #pragma unroll
    for (int nf = 0; nf < 4; nf++)
      #pragma unroll
      for (int r = 0; r < 4; r++) accO[nf][r] *= scalef[r];

    // same-wave LDS write->read ordering (belt & suspenders; DS is in-order)
    asm volatile("s_waitcnt lgkmcnt(0)" ::: "memory");

    // PV: A = P[q][key] (row=lr), B = V[key][dk] read from Vt rows (col=lr=dk)
    const short8 pa0 = *(const short8*)&lP[w][lr][lg * 8];
    const short8 pa1 = *(const short8*)&lP[w][lr][32 + lg * 8];
    #pragma unroll
    for (int nf = 0; nf < 4; nf++) {
      short8 va0 = *(const short8*)&lV[nf * 16 + lr][lg * 8];
      short8 va1 = *(const short8*)&lV[nf * 16 + lr][32 + lg * 8];
      accO[nf] = __builtin_amdgcn_mfma_f32_16x16x32_bf16(pa0, va0, accO[nf], 0, 0, 0);
      accO[nf] = __builtin_amdgcn_mfma_f32_16x16x32_bf16(pa1, va1, accO[nf], 0, 0, 0);
    }
  }

  #pragma unroll
  for (int nf = 0; nf < 4; nf++)
    #pragma unroll
    for (int r = 0; r < 4; r++) {
      float o = accO[nf][r] / lrun[r];
      AO[((size_t)b * Ss + qt * 64 + w * 16 + lg * 4 + r) * Dd + h * DKk + nf * 16 + lr] = f2bf(o);
    }
}

// ---------------------------------------------------------------------------
// 6) Output projection: attn_out(bf16) @ WoT + bo -> d_out (fp32)
// ---------------------------------------------------------------------------
__global__ __launch_bounds__(256) void gemm_out(
    const u16* __restrict__ A, const u16* __restrict__ Bw,
    const float* __restrict__ bo, float* __restrict__ out)
{
  const int mbase = blockIdx.y * 128, nbase = blockIdx.x * 128;
  __shared__ u16 lA[128][40];
  __shared__ u16 lB[128][40];
  const int t = threadIdx.x, lane = t & 63, w = t >> 6;
  const int wr = w >> 1, wc = w & 1, lg = lane >> 4, lr = lane & 15;

  f32x4 acc[4][4];
  #pragma unroll
  for (int mf = 0; mf < 4; mf++)
    #pragma unroll
    for (int nf = 0; nf < 4; nf++) acc[mf][nf] = (f32x4){0.f, 0.f, 0.f, 0.f};

  for (int kk = 0; kk < Dd; kk += 32) {
    #pragma unroll
    for (int i = 0; i < 2; i++) {
      int c = t + 256 * i, row = c >> 2, u = c & 3;
      *(short8*)&lA[row][u * 8] = *(const short8*)(A  + (size_t)(mbase + row) * Dd + kk + u * 8);
      *(short8*)&lB[row][u * 8] = *(const short8*)(Bw + (size_t)(nbase + row) * Dd + kk + u * 8);
    }
    __syncthreads();
    short8 af[4], bfr[4];
    #pragma unroll
    for (int mf = 0; mf < 4; mf++) af[mf]  = *(const short8*)&lA[wr * 64 + mf * 16 + lr][lg * 8];
    #pragma unroll
    for (int nf = 0; nf < 4; nf++) bfr[nf] = *(const short8*)&lB[wc * 64 + nf * 16 + lr][lg * 8];
    #pragma unroll
    for (int mf = 0; mf < 4; mf++)
      #pragma unroll
      for (int nf = 0; nf < 4; nf++)
        acc[mf][nf] = __builtin_amdgcn_mfma_f32_16x16x32_bf16(af[mf], bfr[nf], acc[mf][nf], 0, 0, 0);
    __syncthreads();
  }

  #pragma unroll
  for (int nf = 0; nf < 4; nf++) {
    const int n = nbase + wc * 64 + nf * 16 + lr;
    const float bb = bo[n];
    #pragma unroll
    for (int mf = 0; mf < 4; mf++) {
      const int m0 = mbase + wr * 64 + mf * 16 + lg * 4;
      #pragma unroll
      for (int r = 0; r < 4; r++)
        out[(size_t)(m0 + r) * Dd + n] = acc[mf][nf][r] + bb;
    }
  }
}

// ---------------------------------------------------------------------------
extern "C" void kernel_launch(void* const* d_in, const int* in_sizes, int n_in,
                              void* d_out, int out_size, void* d_ws, size_t ws_size,
                              hipStream_t stream)
{
  (void)in_sizes; (void)n_in; (void)out_size; (void)ws_size;
  const float* q    = (const float*)d_in[0];
  const float* k    = (const float*)d_in[1];
  const float* v    = (const float*)d_in[2];
  const int*   mask = (const int*)  d_in[3];
  const float* Wq   = (const float*)d_in[4];
  const float* bq   = (const float*)d_in[5];
  const float* Wk   = (const float*)d_in[6];
  const float* bk   = (const float*)d_in[7];
  const float* Wv   = (const float*)d_in[8];
  const float* bv   = (const float*)d_in[9];
  const float* Wo   = (const float*)d_in[10];
  const float* bo   = (const float*)d_in[11];

  char* ws = (char*)d_ws;
  u16* A_bf  = (u16*)(ws + 0);          // 3 * 4096*1024 bf16 = 25165824 B
  u16* WT    = (u16*)(ws + 25165824);   // 4 * 1024*1024 bf16 =  8388608 B
  u16* Qh    = (u16*)(ws + 33554432);   // 8388608 B
  u16* Kh    = (u16*)(ws + 41943040);   // 8388608 B
  u16* Vt    = (u16*)(ws + 50331648);   // 8388608 B
  u16* AO    = (u16*)(ws + 58720256);   // 8388608 B
  int* flags = (int*)(ws + 67108864);   // 2048 * 4 B

  cvt_inputs  <<<2048, 256, 0, stream>>>(q, k, v, A_bf);
  wt_transpose<<<dim3(16, 16, 4), 256, 0, stream>>>(Wq, Wk, Wv, Wo, WT);
  mask_flags  <<<2048, 256, 0, stream>>>(mask, flags);
  gemm_qkv    <<<dim3(8, 32, 3), 256, 0, stream>>>(A_bf, WT, bq, bk, bv, Qh, Kh, Vt);
  attn_kernel <<<dim3(32, 16, 2), 256, 0, stream>>>(Qh, Kh, Vt, mask, flags, AO);
  gemm_out    <<<dim3(8, 32), 256, 0, stream>>>(AO, WT + (size_t)3 * Dd * Dd, bo, (float*)d_out);
}